// Round 2
// baseline (385.736 us; speedup 1.0000x reference)
//
#include <hip/hip_runtime.h>

using s4    = __attribute__((ext_vector_type(4))) short;
using s8    = __attribute__((ext_vector_type(8))) short;
using f32x4 = __attribute__((ext_vector_type(4))) float;

__device__ __forceinline__ float bf2f(short u) {
    union { unsigned int i; float f; } c;
    c.i = ((unsigned int)(unsigned short)u) << 16;
    return c.f;
}
__device__ __forceinline__ short f2bf(float f) {
    union { float f; unsigned int i; } c; c.f = f;
    unsigned int x = c.i;
    x += 0x7fffu + ((x >> 16) & 1u);   // round-to-nearest-even
    return (short)(x >> 16);
}

#define MFMA(a, b, c) __builtin_amdgcn_mfma_f32_16x16x32_bf16(a, b, c, 0, 0, 0)

// ---------------- f32 -> bf16 conversion (weights) ----------------
__global__ __launch_bounds__(256) void conv_kernel(const float* __restrict__ in,
                                                   short* __restrict__ out, int n4) {
    int i = blockIdx.x * 256 + threadIdx.x;
    if (i >= n4) return;
    f32x4 v = *(const f32x4*)(in + i * 4);
    s4 o;
    o[0] = f2bf(v[0]); o[1] = f2bf(v[1]); o[2] = f2bf(v[2]); o[3] = f2bf(v[3]);
    *(s4*)(out + i * 4) = o;
}

// ---------------- RMSNorm (T5: no mean-sub, no bias), f32 in -> bf16 out ----------------
__global__ __launch_bounds__(256) void rmsnorm_kernel(const float* __restrict__ x,
                                                      const float* __restrict__ w,
                                                      short* __restrict__ out) {
    int row = blockIdx.x;
    int tid = threadIdx.x;
    const float* xr = x + ((size_t)row << 10);
    f32x4 v = *(const f32x4*)(xr + tid * 4);
    float ss = v[0] * v[0] + v[1] * v[1] + v[2] * v[2] + v[3] * v[3];
#pragma unroll
    for (int off = 32; off > 0; off >>= 1) ss += __shfl_down(ss, off);
    __shared__ float red[4];
    if ((tid & 63) == 0) red[tid >> 6] = ss;
    __syncthreads();
    float total = red[0] + red[1] + red[2] + red[3];
    float r = rsqrtf(total * (1.0f / 1024.0f) + 1e-6f);
    f32x4 wv = *(const f32x4*)(w + tid * 4);
    s4 o;
    o[0] = f2bf(v[0] * r * wv[0]);
    o[1] = f2bf(v[1] * r * wv[1]);
    o[2] = f2bf(v[2] * r * wv[2]);
    o[3] = f2bf(v[3] * r * wv[3]);
    *(s4*)(out + ((size_t)row << 10) + tid * 4) = o;
}

// ---------------- relative-position bias table: table[h][rel+2047] ----------------
__global__ void bias_table_kernel(const float* __restrict__ rel_bias, float* __restrict__ table) {
    int idx = blockIdx.x * 256 + threadIdx.x;   // 0..4094
    if (idx >= 4095) return;
    int rel = idx - 2047;                       // rel = mem - ctx
    int bucket = (rel > 0) ? 16 : 0;
    int a = (rel < 0) ? -rel : rel;
    if (a < 8) {
        bucket += a;
    } else {
        // match f32: log(a/8)/log(16)*8, trunc
        float l = logf((float)a * 0.125f) / 2.772588722239781f * 8.0f;
        int large = 8 + (int)l;
        bucket += (large > 15) ? 15 : large;
    }
#pragma unroll
    for (int h = 0; h < 16; ++h)
        table[h * 4095 + idx] = rel_bias[bucket * 16 + h];
}

// ---------------- 128x128-tile bf16 MFMA GEMM ----------------
// mode 0: Cf = A@B + resid (f32 out, f32 resid)
// mode 1: Cb = A@B, permuted to [b][h][s][dk] (bf16 out)
__global__ __launch_bounds__(256) void gemm_kernel(const short* __restrict__ A,
                                                   const short* __restrict__ B,
                                                   short* __restrict__ Cb,
                                                   float* __restrict__ Cf,
                                                   const float* __restrict__ resid,
                                                   int mode) {
    __shared__ __align__(16) short A_lds[128][40];   // [m][k], pad to 80B rows
    __shared__ __align__(16) short B_lds[128][40];   // transposed: [n][k]
    const int K = 1024, N = 1024;
    int tid = threadIdx.x;
    int m0 = blockIdx.y << 7, n0 = blockIdx.x << 7;
    int wave = tid >> 6, lane = tid & 63;
    int wm = (wave >> 1) << 6, wn = (wave & 1) << 6;
    int lr = lane & 15, lg = lane >> 4;
    int a_row = tid >> 1, a_k = (tid & 1) << 4;
    int b_k = tid & 31, b_n = (tid >> 5) << 4;
    f32x4 acc[4][4] = {};

    for (int kk = 0; kk < K; kk += 32) {
        const short* Ap = A + (size_t)(m0 + a_row) * K + kk + a_k;
        s8 av0 = *(const s8*)Ap;
        s8 av1 = *(const s8*)(Ap + 8);
        const short* Bp = B + (size_t)(kk + b_k) * N + n0 + b_n;
        s8 bv0 = *(const s8*)Bp;
        s8 bv1 = *(const s8*)(Bp + 8);
        __syncthreads();
        *(s8*)&A_lds[a_row][a_k] = av0;
        *(s8*)&A_lds[a_row][a_k + 8] = av1;
#pragma unroll
        for (int j = 0; j < 8; ++j) B_lds[b_n + j][b_k] = bv0[j];
#pragma unroll
        for (int j = 0; j < 8; ++j) B_lds[b_n + 8 + j][b_k] = bv1[j];
        __syncthreads();
        s8 af[4], bfr[4];
#pragma unroll
        for (int i = 0; i < 4; ++i) af[i] = *(const s8*)&A_lds[wm + i * 16 + lr][lg * 8];
#pragma unroll
        for (int i = 0; i < 4; ++i) bfr[i] = *(const s8*)&B_lds[wn + i * 16 + lr][lg * 8];
#pragma unroll
        for (int mi = 0; mi < 4; ++mi)
#pragma unroll
            for (int ni = 0; ni < 4; ++ni)
                acc[mi][ni] = MFMA(af[mi], bfr[ni], acc[mi][ni]);
    }

#pragma unroll
    for (int mi = 0; mi < 4; ++mi) {
#pragma unroll
        for (int ni = 0; ni < 4; ++ni) {
#pragma unroll
            for (int j = 0; j < 4; ++j) {
                int r = m0 + wm + mi * 16 + lg * 4 + j;
                int c = n0 + wn + ni * 16 + lr;
                float v = acc[mi][ni][j];
                if (mode == 0) {
                    size_t idx = ((size_t)r << 10) + c;
                    Cf[idx] = v + resid[idx];
                } else {
                    int b = r >> 11, sdx = r & 2047;
                    int h = c >> 6, d = c & 63;
                    Cb[(((size_t)(b * 16 + h) << 11) + sdx) * 64 + d] = f2bf(v);
                }
            }
        }
    }
}

// ---------------- flash attention: block = (qtile of 64, h, b), 4 waves x 16 q-rows ----------------
__global__ __launch_bounds__(256) void attn_kernel(const short* __restrict__ Q,
                                                   const short* __restrict__ Km,
                                                   const short* __restrict__ Vm,
                                                   const float* __restrict__ table,
                                                   short* __restrict__ ctx) {
    const int S = 2048;
    int qt = blockIdx.x, h = blockIdx.y, b = blockIdx.z;
    int bh = b * 16 + h;
    const short* Qp = Q + (size_t)bh * S * 64;
    const short* Kp = Km + (size_t)bh * S * 64;
    const short* Vp = Vm + (size_t)bh * S * 64;
    const float* tab = table + h * 4095;

    __shared__ __align__(16) short K_lds[64][72];      // [kcol][dk]
    __shared__ __align__(16) short V_lds[64][72];      // transposed: [d][kcol]
    __shared__ __align__(16) short P_lds[4][16][72];   // per-wave P re-fragment buffer

    int tid = threadIdx.x;
    int wave = tid >> 6, lane = tid & 63;
    int lr = lane & 15, lg = lane >> 4;
    int q0 = qt * 64 + wave * 16;

    // preload Q fragments (A-layout: row=lr, k contiguous)
    const short* qrow = Qp + (size_t)(q0 + lr) * 64 + lg * 8;
    s8 qf0 = *(const s8*)(qrow);
    s8 qf1 = *(const s8*)(qrow + 32);

    f32x4 o_acc[4] = {};
    float m_run[4], l_run[4];
#pragma unroll
    for (int j = 0; j < 4; ++j) { m_run[j] = -1e30f; l_run[j] = 0.0f; }

    int k_row = tid >> 2, k_c = (tid & 3) << 4;     // K staging: 64 rows x 4 chunks
    int v_row = tid & 63, v_d = (tid >> 6) << 4;    // V staging: 64 rows x 4 d-chunks

    for (int kt0 = 0; kt0 < S; kt0 += 64) {
        const short* kp = Kp + (size_t)(kt0 + k_row) * 64 + k_c;
        s8 kv0 = *(const s8*)kp;
        s8 kv1 = *(const s8*)(kp + 8);
        const short* vp = Vp + (size_t)(kt0 + v_row) * 64 + v_d;
        s8 vv0 = *(const s8*)vp;
        s8 vv1 = *(const s8*)(vp + 8);
        __syncthreads();
        *(s8*)&K_lds[k_row][k_c] = kv0;
        *(s8*)&K_lds[k_row][k_c + 8] = kv1;
#pragma unroll
        for (int j = 0; j < 8; ++j) V_lds[v_d + j][v_row] = vv0[j];
#pragma unroll
        for (int j = 0; j < 8; ++j) V_lds[v_d + 8 + j][v_row] = vv1[j];
        __syncthreads();

        // QK^T: 16 q-rows x 64 kcols
        f32x4 sc[4];
#pragma unroll
        for (int kt = 0; kt < 4; ++kt) {
            s8 kf0 = *(const s8*)&K_lds[kt * 16 + lr][lg * 8];
            s8 kf1 = *(const s8*)&K_lds[kt * 16 + lr][32 + lg * 8];
            f32x4 s = {};
            s = MFMA(qf0, kf0, s);
            s = MFMA(qf1, kf1, s);
            sc[kt] = s;
        }
        // add relative-position bias
#pragma unroll
        for (int kt = 0; kt < 4; ++kt)
#pragma unroll
            for (int j = 0; j < 4; ++j) {
                int kcol = kt0 + kt * 16 + lr;
                int qr = q0 + lg * 4 + j;
                sc[kt][j] += tab[kcol - qr + 2047];
            }
        // online softmax (row spread across 16 lanes)
        float mt[4];
#pragma unroll
        for (int j = 0; j < 4; ++j)
            mt[j] = fmaxf(fmaxf(sc[0][j], sc[1][j]), fmaxf(sc[2][j], sc[3][j]));
#pragma unroll
        for (int msk = 1; msk <= 8; msk <<= 1)
#pragma unroll
            for (int j = 0; j < 4; ++j) mt[j] = fmaxf(mt[j], __shfl_xor(mt[j], msk));
        float scale[4], rsum[4];
#pragma unroll
        for (int j = 0; j < 4; ++j) {
            float mn = fmaxf(m_run[j], mt[j]);
            scale[j] = __expf(m_run[j] - mn);
            m_run[j] = mn;
            rsum[j] = 0.0f;
        }
#pragma unroll
        for (int kt = 0; kt < 4; ++kt)
#pragma unroll
            for (int j = 0; j < 4; ++j) {
                float p = __expf(sc[kt][j] - m_run[j]);
                sc[kt][j] = p;
                rsum[j] += p;
            }
#pragma unroll
        for (int msk = 1; msk <= 8; msk <<= 1)
#pragma unroll
            for (int j = 0; j < 4; ++j) rsum[j] += __shfl_xor(rsum[j], msk);
#pragma unroll
        for (int j = 0; j < 4; ++j) l_run[j] = l_run[j] * scale[j] + rsum[j];
#pragma unroll
        for (int dt = 0; dt < 4; ++dt)
#pragma unroll
            for (int j = 0; j < 4; ++j) o_acc[dt][j] *= scale[j];
        // P -> bf16 -> LDS (D-layout: row=lg*4+j, col=kt*16+lr)
#pragma unroll
        for (int kt = 0; kt < 4; ++kt)
#pragma unroll
            for (int j = 0; j < 4; ++j)
                P_lds[wave][lg * 4 + j][kt * 16 + lr] = f2bf(sc[kt][j]);
        // PV: P[16x64] @ V[64x64]
        s8 pf0 = *(const s8*)&P_lds[wave][lr][lg * 8];
        s8 pf1 = *(const s8*)&P_lds[wave][lr][32 + lg * 8];
#pragma unroll
        for (int dt = 0; dt < 4; ++dt) {
            s8 vf0 = *(const s8*)&V_lds[dt * 16 + lr][lg * 8];
            s8 vf1 = *(const s8*)&V_lds[dt * 16 + lr][32 + lg * 8];
            o_acc[dt] = MFMA(pf0, vf0, o_acc[dt]);
            o_acc[dt] = MFMA(pf1, vf1, o_acc[dt]);
        }
    }

    // epilogue: normalize and write ctx as [b][s][h*64+d]
#pragma unroll
    for (int dt = 0; dt < 4; ++dt)
#pragma unroll
        for (int j = 0; j < 4; ++j) {
            int r = q0 + lg * 4 + j;
            int c = h * 64 + dt * 16 + lr;
            float v = o_acc[dt][j] / l_run[j];
            ctx[((size_t)(b * 2048 + r) << 10) + c] = f2bf(v);
        }
}

extern "C" void kernel_launch(void* const* d_in, const int* in_sizes, int n_in,
                              void* d_out, int out_size, void* d_ws, size_t ws_size,
                              hipStream_t stream) {
    const float* hidden = (const float*)d_in[0];
    const float* ln_w   = (const float*)d_in[1];
    const float* wq     = (const float*)d_in[2];
    const float* wk     = (const float*)d_in[3];
    const float* wv     = (const float*)d_in[4];
    const float* wo     = (const float*)d_in[5];
    const float* relb   = (const float*)d_in[6];
    float* out = (float*)d_out;

    char* ws = (char*)d_ws;
    const size_t SZ = 8388608;                 // 4096*1024*2 bytes (bf16)
    const size_t WSZ = 2097152;                // 1024*1024*2 bytes (bf16)
    short* normed = (short*)(ws);
    short* q      = (short*)(ws + SZ);
    short* k      = (short*)(ws + 2 * SZ);
    short* v      = (short*)(ws + 3 * SZ);
    short* ctx    = (short*)(ws + 4 * SZ);
    short* wq_b   = (short*)(ws + 5 * SZ);
    short* wk_b   = (short*)(ws + 5 * SZ + WSZ);
    short* wv_b   = (short*)(ws + 5 * SZ + 2 * WSZ);
    short* wo_b   = (short*)(ws + 5 * SZ + 3 * WSZ);
    float* table  = (float*)(ws + 5 * SZ + 4 * WSZ);   // 16*4095*4 = 262080 B

    conv_kernel<<<1024, 256, 0, stream>>>(wq, wq_b, 262144);
    conv_kernel<<<1024, 256, 0, stream>>>(wk, wk_b, 262144);
    conv_kernel<<<1024, 256, 0, stream>>>(wv, wv_b, 262144);
    conv_kernel<<<1024, 256, 0, stream>>>(wo, wo_b, 262144);
    rmsnorm_kernel<<<4096, 256, 0, stream>>>(hidden, ln_w, normed);
    bias_table_kernel<<<16, 256, 0, stream>>>(relb, table);
    dim3 g(8, 32);
    gemm_kernel<<<g, 256, 0, stream>>>(normed, wq_b, q, nullptr, nullptr, 1);
    gemm_kernel<<<g, 256, 0, stream>>>(normed, wk_b, k, nullptr, nullptr, 1);
    gemm_kernel<<<g, 256, 0, stream>>>(normed, wv_b, v, nullptr, nullptr, 1);
    attn_kernel<<<dim3(32, 16, 2), 256, 0, stream>>>(q, k, v, table, ctx);
    gemm_kernel<<<g, 256, 0, stream>>>(ctx, wo_b, nullptr, out, hidden, 0);
}

// Round 5
// 302.836 us; speedup vs baseline: 1.2737x; 1.2737x over previous
//
#include <hip/hip_runtime.h>

using s4     = __attribute__((ext_vector_type(4))) short;
using s8     = __attribute__((ext_vector_type(8))) short;
using f32x4  = __attribute__((ext_vector_type(4))) float;
using f32x4u = __attribute__((ext_vector_type(4), aligned(4))) float;

__device__ __forceinline__ float bf2f(short u) {
    union { unsigned int i; float f; } c;
    c.i = ((unsigned int)(unsigned short)u) << 16;
    return c.f;
}
__device__ __forceinline__ short f2bf(float f) {
    union { float f; unsigned int i; } c; c.f = f;
    unsigned int x = c.i;
    x += 0x7fffu + ((x >> 16) & 1u);   // round-to-nearest-even
    return (short)(x >> 16);
}

#define MFMA(a, b, c) __builtin_amdgcn_mfma_f32_16x16x32_bf16(a, b, c, 0, 0, 0)
#define LOG2E 1.4426950408889634f

// ---------------- f32 [K][N] -> bf16 [N][K] transpose+convert (weights) ----------------
__global__ __launch_bounds__(256) void convT_kernel(const float* __restrict__ in,
                                                    short* __restrict__ out) {
    __shared__ float t[64][65];
    int n0 = blockIdx.x * 64, k0 = blockIdx.y * 64;
    int tx = threadIdx.x & 15, ty = threadIdx.x >> 4;
#pragma unroll
    for (int i = 0; i < 4; ++i) {
        int r = ty + i * 16;                      // k within tile
        f32x4 v = *(const f32x4*)(in + (size_t)(k0 + r) * 1024 + n0 + tx * 4);
        t[r][tx * 4 + 0] = v[0]; t[r][tx * 4 + 1] = v[1];
        t[r][tx * 4 + 2] = v[2]; t[r][tx * 4 + 3] = v[3];
    }
    __syncthreads();
#pragma unroll
    for (int i = 0; i < 4; ++i) {
        int r = ty + i * 16;                      // n within tile
        s4 o;
#pragma unroll
        for (int e = 0; e < 4; ++e) o[e] = f2bf(t[tx * 4 + e][r]);
        *(s4*)(out + (size_t)(n0 + r) * 1024 + k0 + tx * 4) = o;
    }
}

// ---------------- RMSNorm f32 in -> bf16 out ----------------
__global__ __launch_bounds__(256) void rmsnorm_kernel(const float* __restrict__ x,
                                                      const float* __restrict__ w,
                                                      short* __restrict__ out) {
    int row = blockIdx.x;
    int tid = threadIdx.x;
    const float* xr = x + ((size_t)row << 10);
    f32x4 v = *(const f32x4*)(xr + tid * 4);
    float ss = v[0] * v[0] + v[1] * v[1] + v[2] * v[2] + v[3] * v[3];
#pragma unroll
    for (int off = 32; off > 0; off >>= 1) ss += __shfl_down(ss, off);
    __shared__ float red[4];
    if ((tid & 63) == 0) red[tid >> 6] = ss;
    __syncthreads();
    float total = red[0] + red[1] + red[2] + red[3];
    float r = rsqrtf(total * (1.0f / 1024.0f) + 1e-6f);
    f32x4 wv = *(const f32x4*)(w + tid * 4);
    s4 o;
    o[0] = f2bf(v[0] * r * wv[0]);
    o[1] = f2bf(v[1] * r * wv[1]);
    o[2] = f2bf(v[2] * r * wv[2]);
    o[3] = f2bf(v[3] * r * wv[3]);
    *(s4*)(out + ((size_t)row << 10) + tid * 4) = o;
}

// ---------------- reversed bias table: tabR[h][q - k + 2047] = bias(rel=k-q) * LOG2E ----------------
__global__ void bias_table_kernel(const float* __restrict__ rel_bias, float* __restrict__ table) {
    int idx = blockIdx.x * 256 + threadIdx.x;   // 0..4094
    if (idx >= 4095) return;
    int rel = 2047 - idx;                       // rel = mem(k) - ctx(q)
    int bucket = (rel > 0) ? 16 : 0;
    int a = (rel < 0) ? -rel : rel;
    if (a < 8) {
        bucket += a;
    } else {
        float l = logf((float)a * 0.125f) / 2.772588722239781f * 8.0f;
        int large = 8 + (int)l;
        bucket += (large > 15) ? 15 : large;
    }
#pragma unroll
    for (int h = 0; h < 16; ++h)
        table[h * 4095 + idx] = rel_bias[bucket * 16 + h] * LOG2E;
}

// ---------------- 128x128-tile bf16 MFMA GEMM, B pre-transposed [N][K] ----------------
// mode 0: Cf = A@B + resid (f32 out)
// mode 1: Cb = A@B  -> [b][h][s][dk] bf16      (K)
// mode 2: Cb = A@B * LOG2E -> [b][h][s][dk]    (Q)
// mode 3: Cb = A@B  -> [b][h][dk][s] bf16      (V^T)
__global__ __launch_bounds__(256) void gemm_kernel(const short* __restrict__ A,
                                                   const short* __restrict__ Bt,
                                                   short* __restrict__ Cb,
                                                   float* __restrict__ Cf,
                                                   const float* __restrict__ resid,
                                                   int mode) {
    __shared__ __align__(16) short A_lds[128][40];
    __shared__ __align__(16) short B_lds[128][40];
    const int K = 1024;
    int tid = threadIdx.x;
    int m0 = blockIdx.y << 7, n0 = blockIdx.x << 7;
    int wave = tid >> 6, lane = tid & 63;
    int wm = (wave >> 1) << 6, wn = (wave & 1) << 6;
    int lr = lane & 15, lg = lane >> 4;
    int row = tid >> 1, ch = (tid & 1) << 4;
    f32x4 acc[4][4] = {};

    const short* Ap = A + (size_t)(m0 + row) * K + ch;
    const short* Bp = Bt + (size_t)(n0 + row) * K + ch;
    s8 av0 = *(const s8*)Ap,       av1 = *(const s8*)(Ap + 8);
    s8 bv0 = *(const s8*)Bp,       bv1 = *(const s8*)(Bp + 8);

    for (int kk = 0; kk < K; kk += 32) {
        __syncthreads();
        *(s8*)&A_lds[row][ch] = av0;  *(s8*)&A_lds[row][ch + 8] = av1;
        *(s8*)&B_lds[row][ch] = bv0;  *(s8*)&B_lds[row][ch + 8] = bv1;
        int kn = (kk + 32 < K) ? kk + 32 : kk;     // T14: issue next-tile loads pre-compute
        av0 = *(const s8*)(Ap + kn); av1 = *(const s8*)(Ap + kn + 8);
        bv0 = *(const s8*)(Bp + kn); bv1 = *(const s8*)(Bp + kn + 8);
        __syncthreads();
        s8 af[4], bfr[4];
#pragma unroll
        for (int i = 0; i < 4; ++i) af[i]  = *(const s8*)&A_lds[wm + i * 16 + lr][lg * 8];
#pragma unroll
        for (int i = 0; i < 4; ++i) bfr[i] = *(const s8*)&B_lds[wn + i * 16 + lr][lg * 8];
#pragma unroll
        for (int mi = 0; mi < 4; ++mi)
#pragma unroll
            for (int ni = 0; ni < 4; ++ni)
                acc[mi][ni] = MFMA(af[mi], bfr[ni], acc[mi][ni]);
    }

#pragma unroll
    for (int mi = 0; mi < 4; ++mi) {
#pragma unroll
        for (int ni = 0; ni < 4; ++ni) {
#pragma unroll
            for (int j = 0; j < 4; ++j) {
                int r = m0 + wm + mi * 16 + lg * 4 + j;
                int c = n0 + wn + ni * 16 + lr;
                float v = acc[mi][ni][j];
                if (mode == 0) {
                    size_t idx = ((size_t)r << 10) + c;
                    Cf[idx] = v + resid[idx];
                } else {
                    int b = r >> 11, sdx = r & 2047;
                    int h = c >> 6, d = c & 63;
                    if (mode == 3) {
                        Cb[((size_t)((b * 16 + h) * 64 + d) << 11) + sdx] = f2bf(v);
                    } else {
                        if (mode == 2) v *= LOG2E;
                        Cb[(((size_t)(b * 16 + h) << 11) + sdx) * 64 + d] = f2bf(v);
                    }
                }
            }
        }
    }
}

// ---------------- flash attention (log2 domain, defer-max, swizzled V^T LDS) ----------------
__global__ __launch_bounds__(256) void attn_kernel(const short* __restrict__ Q,
                                                   const short* __restrict__ Km,
                                                   const short* __restrict__ VT,
                                                   const float* __restrict__ tabR,
                                                   short* __restrict__ ctx) {
    const int S = 2048;
    int bid = blockIdx.x;
    // XCD-aware remap: all 32 q-tiles of one (b,h) land on one XCD
    int qt = bid >> 5;
    int bh = ((bid & 7) << 2) | ((bid >> 3) & 3);
    int b = bh >> 4, h = bh & 15;
    const short* Qp = Q  + (size_t)bh * S * 64;
    const short* Kp = Km + (size_t)bh * S * 64;
    const short* Vp = VT + (size_t)bh * 64 * S;     // [d][s]
    const float* tb0 = tabR + h * 4095;

    __shared__ __align__(16) short K_lds[64][72];     // [k][dk] padded
    __shared__ __align__(16) short V_lds[64 * 64];    // [d][k] linear, XOR-swizzled 16B blocks
    __shared__ __align__(16) short P_lds[4][16][72];

    int tid = threadIdx.x;
    int wave = tid >> 6, lane = tid & 63;
    int lr = lane & 15, lg = lane >> 4;
    int q0 = qt * 64 + wave * 16;

    const short* qrow = Qp + (size_t)(q0 + lr) * 64 + lg * 8;
    s8 qf0 = *(const s8*)(qrow);
    s8 qf1 = *(const s8*)(qrow + 32);

    f32x4 o_acc[4] = {};
    float m_run[4], l_part[4];
#pragma unroll
    for (int j = 0; j < 4; ++j) { m_run[j] = -1e30f; l_part[j] = 0.0f; }

    int k_row = tid >> 2, k_c = (tid & 3) << 4;          // K staging
    int v_d = tid >> 2, v_kc = (tid & 3) << 4;           // V^T staging: row d, k-chunk
    int kb0 = v_kc >> 3;                                 // 16B block index (0,2,4,6)
    int v_wr0 = v_d * 128 + ((kb0 ^ (v_d & 7)) << 4);
    int v_wr1 = v_d * 128 + (((kb0 + 1) ^ (v_d & 7)) << 4);

    // prologue loads (tile 0)
    const short* kp = Kp + (size_t)k_row * 64 + k_c;
    s8 kv0 = *(const s8*)kp, kv1 = *(const s8*)(kp + 8);
    const short* vp = Vp + (size_t)v_d * S + v_kc;
    s8 vv0 = *(const s8*)vp, vv1 = *(const s8*)(vp + 8);

    for (int kt0 = 0; kt0 < S; kt0 += 64) {
        __syncthreads();
        *(s8*)&K_lds[k_row][k_c] = kv0;
        *(s8*)&K_lds[k_row][k_c + 8] = kv1;
        *(s8*)((char*)V_lds + v_wr0) = vv0;
        *(s8*)((char*)V_lds + v_wr1) = vv1;
        int nt = (kt0 + 64 < S) ? kt0 + 64 : kt0;        // T14 prefetch
        kv0 = *(const s8*)(kp + (size_t)nt * 64);
        kv1 = *(const s8*)(kp + (size_t)nt * 64 + 8);
        vv0 = *(const s8*)(vp + nt);
        vv1 = *(const s8*)(vp + nt + 8);
        __syncthreads();

        // bias vectors: tabR[h][ (q0+lg*4+j) - (kt0+kt*16+lr) + 2047 ]
        const float* tb = tb0 + (q0 + lg * 4 - kt0 - lr + 2047);
        f32x4u bias[4];
#pragma unroll
        for (int kt = 0; kt < 4; ++kt) bias[kt] = *(const f32x4u*)(tb - kt * 16);

        // QK^T (log2-domain: Q pre-scaled by LOG2E)
        f32x4 sc[4];
        __builtin_amdgcn_s_setprio(1);
#pragma unroll
        for (int kt = 0; kt < 4; ++kt) {
            s8 kf0 = *(const s8*)&K_lds[kt * 16 + lr][lg * 8];
            s8 kf1 = *(const s8*)&K_lds[kt * 16 + lr][32 + lg * 8];
            f32x4 s = {};
            s = MFMA(qf0, kf0, s);
            s = MFMA(qf1, kf1, s);
            sc[kt] = s;
        }
        __builtin_amdgcn_s_setprio(0);
#pragma unroll
        for (int kt = 0; kt < 4; ++kt)
#pragma unroll
            for (int j = 0; j < 4; ++j) sc[kt][j] += bias[kt][j];

        // tile row-max over 16 lanes
        float mt[4];
#pragma unroll
        for (int j = 0; j < 4; ++j)
            mt[j] = fmaxf(fmaxf(sc[0][j], sc[1][j]), fmaxf(sc[2][j], sc[3][j]));
#pragma unroll
        for (int msk = 1; msk <= 8; msk <<= 1)
#pragma unroll
            for (int j = 0; j < 4; ++j) mt[j] = fmaxf(mt[j], __shfl_xor(mt[j], msk));

        // defer-max (THR = 11 in log2 units)
        bool need = false;
#pragma unroll
        for (int j = 0; j < 4; ++j) need |= (mt[j] > m_run[j] + 11.0f);
        if (__any(need)) {
#pragma unroll
            for (int j = 0; j < 4; ++j) {
                float mn = fmaxf(m_run[j], mt[j]);
                float scale = exp2f(m_run[j] - mn);
                m_run[j] = mn;
                l_part[j] *= scale;
#pragma unroll
                for (int dt = 0; dt < 4; ++dt) o_acc[dt][j] *= scale;
            }
        }

        // P = exp2(s - m); accumulate per-lane partial l
#pragma unroll
        for (int kt = 0; kt < 4; ++kt)
#pragma unroll
            for (int j = 0; j < 4; ++j) {
                float p = exp2f(sc[kt][j] - m_run[j]);
                sc[kt][j] = p;
                l_part[j] += p;
            }

        // P -> bf16 -> LDS (D-layout: row=lg*4+j, col=kt*16+lr)
#pragma unroll
        for (int kt = 0; kt < 4; ++kt)
#pragma unroll
            for (int j = 0; j < 4; ++j)
                P_lds[wave][lg * 4 + j][kt * 16 + lr] = f2bf(sc[kt][j]);

        // PV with swizzled V^T reads
        s8 pf0 = *(const s8*)&P_lds[wave][lr][lg * 8];
        s8 pf1 = *(const s8*)&P_lds[wave][lr][32 + lg * 8];
        __builtin_amdgcn_s_setprio(1);
#pragma unroll
        for (int dt = 0; dt < 4; ++dt) {
            int d = dt * 16 + lr;
            s8 vf0 = *(const s8*)((char*)V_lds + d * 128 + ((lg ^ (lr & 7)) << 4));
            s8 vf1 = *(const s8*)((char*)V_lds + d * 128 + (((4 + lg) ^ (lr & 7)) << 4));
            o_acc[dt] = MFMA(pf0, vf0, o_acc[dt]);
            o_acc[dt] = MFMA(pf1, vf1, o_acc[dt]);
        }
        __builtin_amdgcn_s_setprio(0);
    }

    // final l reduction across 16 lanes
#pragma unroll
    for (int msk = 1; msk <= 8; msk <<= 1)
#pragma unroll
        for (int j = 0; j < 4; ++j) l_part[j] += __shfl_xor(l_part[j], msk);

#pragma unroll
    for (int dt = 0; dt < 4; ++dt)
#pragma unroll
        for (int j = 0; j < 4; ++j) {
            int r = q0 + lg * 4 + j;
            int c = h * 64 + dt * 16 + lr;
            float v = o_acc[dt][j] / l_part[j];
            ctx[((size_t)(b * 2048 + r) << 10) + c] = f2bf(v);
        }
}

extern "C" void kernel_launch(void* const* d_in, const int* in_sizes, int n_in,
                              void* d_out, int out_size, void* d_ws, size_t ws_size,
                              hipStream_t stream) {
    const float* hidden = (const float*)d_in[0];
    const float* ln_w   = (const float*)d_in[1];
    const float* wq     = (const float*)d_in[2];
    const float* wk     = (const float*)d_in[3];
    const float* wv     = (const float*)d_in[4];
    const float* wo     = (const float*)d_in[5];
    const float* relb   = (const float*)d_in[6];
    float* out = (float*)d_out;

    char* ws = (char*)d_ws;
    const size_t SZ = 8388608;                 // 4096*1024*2 bytes (bf16)
    const size_t WSZ = 2097152;                // 1024*1024*2 bytes (bf16)
    short* normed = (short*)(ws);
    short* q      = (short*)(ws + SZ);
    short* k      = (short*)(ws + 2 * SZ);
    short* vt     = (short*)(ws + 3 * SZ);
    short* ctx    = (short*)(ws + 4 * SZ);
    short* wq_t   = (short*)(ws + 5 * SZ);
    short* wk_t   = (short*)(ws + 5 * SZ + WSZ);
    short* wv_t   = (short*)(ws + 5 * SZ + 2 * WSZ);
    short* wo_t   = (short*)(ws + 5 * SZ + 3 * WSZ);
    float* table  = (float*)(ws + 5 * SZ + 4 * WSZ);   // 16*4095*4 B

    dim3 tg(16, 16);
    convT_kernel<<<tg, 256, 0, stream>>>(wq, wq_t);
    convT_kernel<<<tg, 256, 0, stream>>>(wk, wk_t);
    convT_kernel<<<tg, 256, 0, stream>>>(wv, wv_t);
    convT_kernel<<<tg, 256, 0, stream>>>(wo, wo_t);
    rmsnorm_kernel<<<4096, 256, 0, stream>>>(hidden, ln_w, normed);
    bias_table_kernel<<<16, 256, 0, stream>>>(relb, table);
    dim3 g(8, 32);
    gemm_kernel<<<g, 256, 0, stream>>>(normed, wq_t, q,   nullptr, nullptr, 2);
    gemm_kernel<<<g, 256, 0, stream>>>(normed, wk_t, k,   nullptr, nullptr, 1);
    gemm_kernel<<<g, 256, 0, stream>>>(normed, wv_t, vt,  nullptr, nullptr, 3);
    attn_kernel<<<1024, 256, 0, stream>>>(q, k, vt, table, ctx);
    gemm_kernel<<<g, 256, 0, stream>>>(ctx, wo_t, nullptr, out, hidden, 0);
}

// Round 6
// 244.696 us; speedup vs baseline: 1.5764x; 1.2376x over previous
//
#include <hip/hip_runtime.h>

using s4     = __attribute__((ext_vector_type(4))) short;
using s8     = __attribute__((ext_vector_type(8))) short;
using f32x4  = __attribute__((ext_vector_type(4))) float;
using f32x4u = __attribute__((ext_vector_type(4), aligned(4))) float;

__device__ __forceinline__ float bf2f(short u) {
    union { unsigned int i; float f; } c;
    c.i = ((unsigned int)(unsigned short)u) << 16;
    return c.f;
}
__device__ __forceinline__ short f2bf(float f) {
    union { float f; unsigned int i; } c; c.f = f;
    unsigned int x = c.i;
    x += 0x7fffu + ((x >> 16) & 1u);   // round-to-nearest-even
    return (short)(x >> 16);
}
__device__ __forceinline__ unsigned int cvt_pk_bf16(float lo, float hi) {
    unsigned int r;
    asm("v_cvt_pk_bf16_f32 %0, %1, %2" : "=v"(r) : "v"(lo), "v"(hi));
    return r;
}
// async global->LDS, 16B per lane; lds dest = wave-uniform base + lane*16
__device__ __forceinline__ void gload16(const short* g, const char* lds) {
    __builtin_amdgcn_global_load_lds(
        (const __attribute__((address_space(1))) unsigned int*)(unsigned long long)(const void*)g,
        (__attribute__((address_space(3))) unsigned int*)(unsigned int)(unsigned long long)(const void*)lds,
        16, 0, 0);
}

#define MFMA(a, b, c) __builtin_amdgcn_mfma_f32_16x16x32_bf16(a, b, c, 0, 0, 0)
#define LOG2E 1.4426950408889634f

// ---------------- f32 [K][N] -> bf16 [N][K] transpose+convert (weights) ----------------
__global__ __launch_bounds__(256) void convT_kernel(const float* __restrict__ in,
                                                    short* __restrict__ out) {
    __shared__ float t[64][65];
    int n0 = blockIdx.x * 64, k0 = blockIdx.y * 64;
    int tx = threadIdx.x & 15, ty = threadIdx.x >> 4;
#pragma unroll
    for (int i = 0; i < 4; ++i) {
        int r = ty + i * 16;                      // k within tile
        f32x4 v = *(const f32x4*)(in + (size_t)(k0 + r) * 1024 + n0 + tx * 4);
        t[r][tx * 4 + 0] = v[0]; t[r][tx * 4 + 1] = v[1];
        t[r][tx * 4 + 2] = v[2]; t[r][tx * 4 + 3] = v[3];
    }
    __syncthreads();
#pragma unroll
    for (int i = 0; i < 4; ++i) {
        int r = ty + i * 16;                      // n within tile
        s4 o;
#pragma unroll
        for (int e = 0; e < 4; ++e) o[e] = f2bf(t[tx * 4 + e][r]);
        *(s4*)(out + (size_t)(n0 + r) * 1024 + k0 + tx * 4) = o;
    }
}

// ---------------- RMSNorm f32 in -> bf16 out ----------------
__global__ __launch_bounds__(256) void rmsnorm_kernel(const float* __restrict__ x,
                                                      const float* __restrict__ w,
                                                      short* __restrict__ out) {
    int row = blockIdx.x;
    int tid = threadIdx.x;
    const float* xr = x + ((size_t)row << 10);
    f32x4 v = *(const f32x4*)(xr + tid * 4);
    float ss = v[0] * v[0] + v[1] * v[1] + v[2] * v[2] + v[3] * v[3];
#pragma unroll
    for (int off = 32; off > 0; off >>= 1) ss += __shfl_down(ss, off);
    __shared__ float red[4];
    if ((tid & 63) == 0) red[tid >> 6] = ss;
    __syncthreads();
    float total = red[0] + red[1] + red[2] + red[3];
    float r = rsqrtf(total * (1.0f / 1024.0f) + 1e-6f);
    f32x4 wv = *(const f32x4*)(w + tid * 4);
    s4 o;
    o[0] = f2bf(v[0] * r * wv[0]);
    o[1] = f2bf(v[1] * r * wv[1]);
    o[2] = f2bf(v[2] * r * wv[2]);
    o[3] = f2bf(v[3] * r * wv[3]);
    *(s4*)(out + ((size_t)row << 10) + tid * 4) = o;
}

// ---------------- reversed bias table: tabR[h][q - k + 2047] = bias(rel=k-q) * LOG2E ----------------
__global__ void bias_table_kernel(const float* __restrict__ rel_bias, float* __restrict__ table) {
    int idx = blockIdx.x * 256 + threadIdx.x;   // 0..4094
    if (idx >= 4095) return;
    int rel = 2047 - idx;                       // rel = mem(k) - ctx(q)
    int bucket = (rel > 0) ? 16 : 0;
    int a = (rel < 0) ? -rel : rel;
    if (a < 8) {
        bucket += a;
    } else {
        float l = logf((float)a * 0.125f) / 2.772588722239781f * 8.0f;
        int large = 8 + (int)l;
        bucket += (large > 15) ? 15 : large;
    }
#pragma unroll
    for (int h = 0; h < 16; ++h)
        table[h * 4095 + idx] = rel_bias[bucket * 16 + h] * LOG2E;
}

// ---------------- 128xBN-tile bf16 MFMA GEMM, global_load_lds + XOR-swizzle, BK=64 ----------------
// MODE 0: Cf = A@B + resid (f32 out), B = wo_t
// MODE 1: fused QKV: B = wqkv_t [3072][1024]; col<1024 -> Q(*LOG2E), <2048 -> K, else V^T
template<int BN, int WROWS, int WCOLS, int MODE>
__global__ __launch_bounds__(256) void gemm2(const short* __restrict__ A,
                                             const short* __restrict__ Bt,
                                             short* __restrict__ oq,
                                             short* __restrict__ ok,
                                             short* __restrict__ ov,
                                             float* __restrict__ Cf,
                                             const float* __restrict__ resid) {
    constexpr int MI = 128 / WROWS / 16;
    constexpr int NI = BN / WCOLS / 16;
    constexpr int NA = 4;          // A gload insts per wave (16KB / 4KB/wave-inst / 4 waves)
    constexpr int NB = BN / 32;    // B gload insts per wave
    const int K = 1024;
    __shared__ __align__(16) char lds[(128 + BN) * 128];   // A then B, rows of 128B
    char* A_base = lds;
    char* B_base = lds + 128 * 128;

    int tid = threadIdx.x;
    int m0 = blockIdx.y << 7, n0 = blockIdx.x * BN;
    int w = tid >> 6, l = tid & 63;
    int lr = l & 15, lg = l >> 4;
    int wm = (w / WCOLS) * (128 / WROWS);
    int wn = (w % WCOLS) * (BN / WCOLS);
    int sr = l >> 3;                 // staging sub-row 0..7
    int cs = (l & 7) ^ sr;           // pre-swizzled source chunk

    f32x4 acc[MI][NI] = {};

    for (int kk = 0; kk < K; kk += 64) {
        __syncthreads();
#pragma unroll
        for (int i = 0; i < NA; ++i) {
            int r = (w * NA + i) * 8 + sr;
            gload16(A + (size_t)(m0 + r) * K + kk + cs * 8, A_base + (w * NA + i) * 1024);
        }
#pragma unroll
        for (int i = 0; i < NB; ++i) {
            int r = (w * NB + i) * 8 + sr;
            gload16(Bt + (size_t)(n0 + r) * K + kk + cs * 8, B_base + (w * NB + i) * 1024);
        }
        __syncthreads();

        s8 af[2][MI], bfv[2][NI];
#pragma unroll
        for (int ks = 0; ks < 2; ++ks) {
            int chunk = ((ks * 4 + lg) ^ (lr & 7)) << 4;
#pragma unroll
            for (int mi = 0; mi < MI; ++mi)
                af[ks][mi] = *(const s8*)(A_base + (wm + mi * 16 + lr) * 128 + chunk);
#pragma unroll
            for (int ni = 0; ni < NI; ++ni)
                bfv[ks][ni] = *(const s8*)(B_base + (wn + ni * 16 + lr) * 128 + chunk);
        }
#pragma unroll
        for (int ks = 0; ks < 2; ++ks)
#pragma unroll
            for (int mi = 0; mi < MI; ++mi)
#pragma unroll
                for (int ni = 0; ni < NI; ++ni)
                    acc[mi][ni] = MFMA(af[ks][mi], bfv[ks][ni], acc[mi][ni]);
    }

#pragma unroll
    for (int mi = 0; mi < MI; ++mi) {
#pragma unroll
        for (int ni = 0; ni < NI; ++ni) {
#pragma unroll
            for (int j = 0; j < 4; ++j) {
                int r = m0 + wm + mi * 16 + lg * 4 + j;
                int c = n0 + wn + ni * 16 + lr;
                float v = acc[mi][ni][j];
                if (MODE == 0) {
                    size_t idx = ((size_t)r << 10) + c;
                    Cf[idx] = v + resid[idx];
                } else {
                    int b = r >> 11, sdx = r & 2047;
                    int which = c >> 10, nn = c & 1023;
                    int h = nn >> 6, d = nn & 63;
                    if (which == 0)
                        oq[(((size_t)(b * 16 + h) << 11) + sdx) * 64 + d] = f2bf(v * LOG2E);
                    else if (which == 1)
                        ok[(((size_t)(b * 16 + h) << 11) + sdx) * 64 + d] = f2bf(v);
                    else
                        ov[((size_t)((b * 16 + h) * 64 + d) << 11) + sdx] = f2bf(v);
                }
            }
        }
    }
}

// ---------------- flash attention, swapped operands (S^T / O^T), scalar softmax state ----------------
__global__ __launch_bounds__(256) void attn_kernel(const short* __restrict__ Q,
                                                   const short* __restrict__ Km,
                                                   const short* __restrict__ VT,
                                                   const float* __restrict__ tabR,
                                                   short* __restrict__ ctx) {
    const int S = 2048;
    int bid = blockIdx.x;
    // XCD-aware remap: all 32 q-tiles of one (b,h) land on one XCD
    int qt = bid >> 5;
    int bh = ((bid & 7) << 2) | ((bid >> 3) & 3);
    int b = bh >> 4, h = bh & 15;
    const short* Qp = Q  + (size_t)bh * S * 64;
    const short* Kp = Km + (size_t)bh * S * 64;
    const short* Vp = VT + (size_t)bh * 64 * S;     // [d][s]
    const float* tb0 = tabR + h * 4095;

    __shared__ __align__(16) short K_lds[64][72];     // [kcol][dk] padded (144B rows)
    __shared__ __align__(16) short V_lds[64 * 64];    // [d][k] linear, XOR-swizzled 16B blocks
    __shared__ __align__(16) short P_lds[4][16][72];  // per-wave P[q][k], 144B rows

    int tid = threadIdx.x;
    int wave = tid >> 6, lane = tid & 63;
    int lr = lane & 15, lg = lane >> 4;
    int q0 = qt * 64 + wave * 16;

    // Q fragments (B-operand: col=lr=q, k=lg*8+e)
    const short* qrow = Qp + (size_t)(q0 + lr) * 64 + lg * 8;
    s8 qf0 = *(const s8*)(qrow);
    s8 qf1 = *(const s8*)(qrow + 32);

    f32x4 o_acc[4] = {};        // o_acc[dt][j]: d = dt*16+lg*4+j, q = lr
    float m_run = -1e30f, l_run = 0.0f;   // per-lane state for q = q0+lr

    int k_row = tid >> 2, k_c = (tid & 3) << 4;          // K staging
    int v_d = tid >> 2, v_kc = (tid & 3) << 4;           // V^T staging
    int kb0 = v_kc >> 3;                                 // 16B block index (0,2,4,6)
    int v_wr0 = v_d * 128 + ((kb0 ^ (v_d & 7)) << 4);
    int v_wr1 = v_d * 128 + (((kb0 + 1) ^ (v_d & 7)) << 4);

    // prologue loads (tile 0)
    const short* kp = Kp + (size_t)k_row * 64 + k_c;
    s8 kv0 = *(const s8*)kp, kv1 = *(const s8*)(kp + 8);
    const short* vp = Vp + (size_t)v_d * S + v_kc;
    s8 vv0 = *(const s8*)vp, vv1 = *(const s8*)(vp + 8);

    char* pbase = (char*)P_lds + wave * 2304 + lr * 144;

    for (int kt0 = 0; kt0 < S; kt0 += 64) {
        __syncthreads();
        *(s8*)&K_lds[k_row][k_c] = kv0;
        *(s8*)&K_lds[k_row][k_c + 8] = kv1;
        *(s8*)((char*)V_lds + v_wr0) = vv0;
        *(s8*)((char*)V_lds + v_wr1) = vv1;
        int nt = (kt0 + 64 < S) ? kt0 + 64 : kt0;        // T14 prefetch
        kv0 = *(const s8*)(kp + (size_t)nt * 64);
        kv1 = *(const s8*)(kp + (size_t)nt * 64 + 8);
        vv0 = *(const s8*)(vp + nt);
        vv1 = *(const s8*)(vp + nt + 8);
        __syncthreads();

        // bias: index = (q0+lr) - (kt0 + kt*16 + lg*4 + j) + 2047, descending in j
        const float* tb = tb0 + (q0 + lr - kt0 - lg * 4 + 2044);
        // S^T = K · Q^T: sc[kt][j] = S[kcol = kt0+kt*16+lg*4+j][q = q0+lr]
        f32x4 sc[4];
        __builtin_amdgcn_s_setprio(1);
#pragma unroll
        for (int kt = 0; kt < 4; ++kt) {
            s8 kf0 = *(const s8*)&K_lds[kt * 16 + lr][lg * 8];
            s8 kf1 = *(const s8*)&K_lds[kt * 16 + lr][32 + lg * 8];
            f32x4 s = {};
            s = MFMA(kf0, qf0, s);
            s = MFMA(kf1, qf1, s);
            sc[kt] = s;
        }
        __builtin_amdgcn_s_setprio(0);
#pragma unroll
        for (int kt = 0; kt < 4; ++kt) {
            f32x4u bv = *(const f32x4u*)(tb - kt * 16);
#pragma unroll
            for (int j = 0; j < 4; ++j) sc[kt][j] += bv[3 - j];
        }

        // tile max: 15 in-lane fmax + 2 cross-lg shfl
        float mt = sc[0][0];
#pragma unroll
        for (int kt = 0; kt < 4; ++kt)
#pragma unroll
            for (int j = 0; j < 4; ++j) mt = fmaxf(mt, sc[kt][j]);
        mt = fmaxf(mt, __shfl_xor(mt, 16));
        mt = fmaxf(mt, __shfl_xor(mt, 32));

        // defer-max (THR = 11 log2-units)
        if (__any(mt > m_run + 11.0f)) {
            float mn = fmaxf(m_run, mt);
            float scale = exp2f(m_run - mn);
            m_run = mn;
            l_run *= scale;
#pragma unroll
            for (int dt = 0; dt < 4; ++dt)
#pragma unroll
                for (int j = 0; j < 4; ++j) o_acc[dt][j] *= scale;
        }

        // P = exp2(s - m); pack 4 bf16 -> ds_write_b64 into P_lds[q][k]
#pragma unroll
        for (int kt = 0; kt < 4; ++kt) {
#pragma unroll
            for (int j = 0; j < 4; ++j) {
                float p = exp2f(sc[kt][j] - m_run);
                sc[kt][j] = p;
                l_run += p;
            }
            uint2 pv;
            pv.x = cvt_pk_bf16(sc[kt][0], sc[kt][1]);
            pv.y = cvt_pk_bf16(sc[kt][2], sc[kt][3]);
            *(uint2*)(pbase + kt * 32 + lg * 8) = pv;
        }

        // O^T += V^T · P^T
        s8 pf0 = *(const s8*)(pbase + lg * 16);
        s8 pf1 = *(const s8*)(pbase + 64 + lg * 16);
        __builtin_amdgcn_s_setprio(1);
#pragma unroll
        for (int dt = 0; dt < 4; ++dt) {
            int d = dt * 16 + lr;
            s8 vf0 = *(const s8*)((char*)V_lds + d * 128 + ((lg ^ (lr & 7)) << 4));
            s8 vf1 = *(const s8*)((char*)V_lds + d * 128 + (((4 + lg) ^ (lr & 7)) << 4));
            o_acc[dt] = MFMA(vf0, pf0, o_acc[dt]);
            o_acc[dt] = MFMA(vf1, pf1, o_acc[dt]);
        }
        __builtin_amdgcn_s_setprio(0);
    }

    // total l for q = q0+lr (cross-lg butterfly)
    l_run += __shfl_xor(l_run, 16);
    l_run += __shfl_xor(l_run, 32);
    float rl = 1.0f / l_run;

    // ctx[b][s=q0+lr][h*64 + dt*16+lg*4+j] — packed 8B stores
    short* cbase = ctx + ((size_t)(b * 2048 + q0 + lr) << 10) + h * 64 + lg * 4;
#pragma unroll
    for (int dt = 0; dt < 4; ++dt) {
        s4 o;
#pragma unroll
        for (int j = 0; j < 4; ++j) o[j] = f2bf(o_acc[dt][j] * rl);
        *(s4*)(cbase + dt * 16) = o;
    }
}

extern "C" void kernel_launch(void* const* d_in, const int* in_sizes, int n_in,
                              void* d_out, int out_size, void* d_ws, size_t ws_size,
                              hipStream_t stream) {
    const float* hidden = (const float*)d_in[0];
    const float* ln_w   = (const float*)d_in[1];
    const float* wq     = (const float*)d_in[2];
    const float* wk     = (const float*)d_in[3];
    const float* wv     = (const float*)d_in[4];
    const float* wo     = (const float*)d_in[5];
    const float* relb   = (const float*)d_in[6];
    float* out = (float*)d_out;

    char* ws = (char*)d_ws;
    const size_t SZ  = 8388608;                // 4096*1024*2 bytes (bf16)
    const size_t WSZ = 2097152;                // 1024*1024*2 bytes (bf16)
    short* normed = (short*)(ws);
    short* q      = (short*)(ws + SZ);
    short* k      = (short*)(ws + 2 * SZ);
    short* vt     = (short*)(ws + 3 * SZ);
    short* ctx    = (short*)(ws + 4 * SZ);
    short* wqkv_t = (short*)(ws + 5 * SZ);            // [3072][1024] bf16
    short* wo_t   = (short*)(ws + 5 * SZ + 3 * WSZ);  // [1024][1024] bf16
    float* table  = (float*)(ws + 5 * SZ + 4 * WSZ);  // 16*4095*4 B

    dim3 tg(16, 16);
    convT_kernel<<<tg, 256, 0, stream>>>(wq, wqkv_t);
    convT_kernel<<<tg, 256, 0, stream>>>(wk, wqkv_t + 1024 * 1024);
    convT_kernel<<<tg, 256, 0, stream>>>(wv, wqkv_t + 2 * 1024 * 1024);
    convT_kernel<<<tg, 256, 0, stream>>>(wo, wo_t);
    rmsnorm_kernel<<<4096, 256, 0, stream>>>(hidden, ln_w, normed);
    bias_table_kernel<<<16, 256, 0, stream>>>(relb, table);
    gemm2<128, 2, 2, 1><<<dim3(24, 32), 256, 0, stream>>>(normed, wqkv_t, q, k, vt, nullptr, nullptr);
    attn_kernel<<<1024, 256, 0, stream>>>(q, k, vt, table, ctx);
    gemm2<64, 4, 1, 0><<<dim3(16, 32), 256, 0, stream>>>(ctx, wo_t, nullptr, nullptr, nullptr, out, hidden);
}